// Round 5
// baseline (230.023 us; speedup 1.0000x reference)
//
#include <hip/hip_runtime.h>

// ---------------------------------------------------------------------------
// HIDecoder fused: y=z@Wy^T+by ; lin_{m,v}=einsum(gamma,W{m,v})+b ; gaussian
// log-lik epilogue.  gamma never materialized:
//   Weff[n=t*8+j][k] = sum_y M_j[t][y]*Wy[t*32+y][k],  M_j = Wm(j<4)/Wv(j>=4)
//   beff[n]          = b_j[t,d] + sum_y by[t*32+y]*M_j[t][y]
// => one (32768 x 512 x 256) bf16-MFMA GEMM + elementwise epilogue.
//
// History: R3 weff pre-swizzle (B-frag order). R5 occupancy 33->64% (no dur
// change). R6 coalesced block-wide epilogue. R7 prefetch+nt FAILED: VGPR cap
// 64 (launch_bounds 8 waves/EU) made compiler sink the prefetch; nt stores
// amplified write traffic. Cross-round fit: dur = ~22us fixed + bytes/3.65TB/s
// -> machine-wide phase convoy (exact-resident grid, all blocks lockstep:
// read phase never overlaps write phase).
// R8 (this round): 2-tile pipelined block. Grid 512, each block = 2 x BM=32
// tiles (64-row footprint = R3's, which had ideal write traffic). Double-
// buffered LDS P/Q (16.9KB each; 16-row lin chunks alias the freed a-buf ->
// total 33.8KB). z(tile1) loaded to regs BEFORE GEMM(0) (sched_barrier(0)
// pins it), ds_written to Q after GEMM(0): tile1 reads overlap tile0 compute
// + epilogue; blocks de-phase over time -> reads overlap writes machine-wide.
// __launch_bounds__(512,4) (VGPR cap 128) so pipeline state STAYS in regs.
// bx/miss prefetched per chunk. Plain stores (nt reverted).
// ---------------------------------------------------------------------------

#define Bsz   32768
#define Tsz   64
#define Dsz   4
#define Ysz   32
#define Zsz   256
#define Nsz   512
#define BTtot (Bsz * Tsz)
#define EPS_  1e-3f
#define LOG2PI_ 1.8378770664093453f

#define BM       32            // batch rows per tile
#define NT       512           // threads per block (8 waves)
#define ASTRIDE  264           // ushorts per staged-z row (a-layout)
#define LSTRIDE  524           // ushorts per lin row (16-row chunk layout)
#define BUFSZ    8448          // ushorts per buffer: 32*264 = 8448 >= 16*524

typedef __attribute__((ext_vector_type(4))) float  f32x4;
typedef __attribute__((ext_vector_type(8))) short  short8;
typedef __attribute__((ext_vector_type(2))) unsigned int uint2v;

static __device__ __forceinline__ unsigned short f2bf(float f) {
    unsigned int u = __float_as_uint(f);
    return (unsigned short)((u + 0x7fffu + ((u >> 16) & 1u)) >> 16);   // RNE
}
static __device__ __forceinline__ float bf2f(unsigned short h) {
    return __uint_as_float(((unsigned int)h) << 16);
}
// HW RNE pack: low16 = bf16(a), high16 = bf16(b)
static __device__ __forceinline__ unsigned int cvt_pk_bf16(float a, float b) {
    unsigned int r;
    asm("v_cvt_pk_bf16_f32 %0, %1, %2" : "=v"(r) : "v"(a), "v"(b));
    return r;
}

// ---------------------------------------------------------------------------
// Prep: 64 blocks (one per t) x 256 threads (one per k).
// Writes weff in B-fragment order:
//   addr(n,k) = (((tau*8+kk)*4+q)*16+c)*8 + j,  tau=n>>4, c=n&15,
//   kk=k>>5, q=(k>>3)&3, j=k&7
// ---------------------------------------------------------------------------
__global__ __launch_bounds__(256)
void hidec_prep(const float* __restrict__ Wy, const float* __restrict__ by,
                const float* __restrict__ Wm, const float* __restrict__ bm,
                const float* __restrict__ Wv, const float* __restrict__ bv,
                unsigned short* __restrict__ weff, float* __restrict__ beff) {
    __shared__ float Ml[8][Ysz];
    __shared__ float byl[Ysz];
    const int t   = blockIdx.x;          // 0..63
    const int tid = threadIdx.x;
    {
        int j = tid >> 5, y = tid & 31;
        const float* src = (j < 4) ? Wm : Wv;
        Ml[j][y] = src[(t * Dsz + (j & 3)) * Ysz + y];
    }
    if (tid < Ysz) byl[tid] = by[t * Ysz + tid];
    __syncthreads();

    const int k = tid;                   // 0..255
    const int kk = k >> 5, q = (k >> 3) & 3, je = k & 7;
    float wy[Ysz];
#pragma unroll
    for (int y = 0; y < Ysz; ++y)
        wy[y] = Wy[(size_t)(t * Ysz + y) * Zsz + k];
#pragma unroll
    for (int j = 0; j < 8; ++j) {
        float acc = 0.f;
#pragma unroll
        for (int y = 0; y < Ysz; ++y) acc = fmaf(Ml[j][y], wy[y], acc);
        int n   = t * 8 + j;
        int tau = n >> 4, c = n & 15;
        weff[((((tau * 8 + kk) * 4 + q) * 16 + c) * 8) + je] = f2bf(acc);
    }
    if (tid < 8) {
        int d = tid & 3;
        float s = ((tid < 4) ? bm : bv)[t * Dsz + d];
        for (int y = 0; y < Ysz; ++y) s = fmaf(byl[y], Ml[tid][y], s);
        beff[t * 8 + tid] = s;
    }
}

// ---------------------------------------------------------------------------
// Main: 512 blocks x 512 threads (8 waves). Each block: 2 tiles of BM=32.
// Wave w owns col-tiles w*4..w*4+3 (cols w*64..w*64+63).
// ---------------------------------------------------------------------------
__global__ __launch_bounds__(NT, 4)
void hidec_main(const float* __restrict__ z, const float* __restrict__ bx,
                const int* __restrict__ miss, const float* __restrict__ dmean,
                const float* __restrict__ dvarp, const unsigned short* __restrict__ weff,
                const float* __restrict__ beff, float* __restrict__ out) {
    __shared__ unsigned short buf[2 * BUFSZ];            // 33792 B

    const int tid  = threadIdx.x;
    const int lane = tid & 63;
    const int w    = tid >> 6;           // wave 0..7
    const int c    = lane & 15;
    const int q    = lane >> 4;
    const long brow0 = (long)blockIdx.x * (2 * BM);      // 64 rows per block

    // stage-load index decomposition (same for every tile)
    // idx4 = tid + i*NT -> (r, c4): r = idx4>>6 in 0..31, c4 = idx4&63

    // ---- per-thread epilogue constants (t = lane, fixed) ------------------
    const int t = lane;
    float4 dv4 = *(const float4*)(dvarp + t * 4);
    float4 dm4 = *(const float4*)(dmean + t * 4);
    float dca[4] = {fmaxf(dv4.x, EPS_), fmaxf(dv4.y, EPS_),
                    fmaxf(dv4.z, EPS_), fmaxf(dv4.w, EPS_)};
    float sqa[4] = {sqrtf(dca[0]), sqrtf(dca[1]), sqrtf(dca[2]), sqrtf(dca[3])};
    float dma[4] = {dm4.x, dm4.y, dm4.z, dm4.w};
    float sldv = __logf(dca[0]) + __logf(dca[1]) + __logf(dca[2]) + __logf(dca[3]);
    float bb[4];
#pragma unroll
    for (int ti = 0; ti < 4; ++ti) bb[ti] = beff[w * 64 + ti * 16 + c];

    // ---- stage tile0 -> P -------------------------------------------------
    float4 zr[4];
#pragma unroll
    for (int i = 0; i < 4; ++i) {
        int idx4 = tid + i * NT;
        int r = idx4 >> 6, c4 = idx4 & 63;
        zr[i] = *(const float4*)(z + (brow0 + r) * Zsz + c4 * 4);
    }
    {
        unsigned short* P = buf;
#pragma unroll
        for (int i = 0; i < 4; ++i) {
            int idx4 = tid + i * NT;
            int r = idx4 >> 6, c4 = idx4 & 63;
            uint2v pk;
            pk.x = cvt_pk_bf16(zr[i].x, zr[i].y);
            pk.y = cvt_pk_bf16(zr[i].z, zr[i].w);
            *(uint2v*)&P[r * ASTRIDE + c4 * 4] = pk;
        }
    }
    __syncthreads();

    // b-fragment base: tau0 = w*4 ; per-(tau,kk) block = 512 ushorts
    const unsigned short* wp = weff + ((size_t)(w * 4) * 8) * 512 + lane * 8;

#pragma unroll 1
    for (int it = 0; it < 2; ++it) {
        unsigned short* cur = buf + (it ? BUFSZ : 0);
        unsigned short* nxt = buf + (it ? 0 : BUFSZ);
        const long row0 = brow0 + it * BM;

        // ---- issue z-loads for tile1 BEFORE GEMM(0) (pipeline fill) -------
        if (it == 0) {
#pragma unroll
            for (int i = 0; i < 4; ++i) {
                int idx4 = tid + i * NT;
                int r = idx4 >> 6, c4 = idx4 & 63;
                zr[i] = *(const float4*)(z + (brow0 + BM + r) * Zsz + c4 * 4);
            }
            __builtin_amdgcn_sched_barrier(0);   // don't sink these loads
        }

        // ---- GEMM: 32 x 512 x K=256, bf16 MFMA 16x16x32 -------------------
        f32x4 acc[8];                    // [ti*2 + rowtile]
#pragma unroll
        for (int i = 0; i < 8; ++i) acc[i] = (f32x4){0.f, 0.f, 0.f, 0.f};

#pragma unroll
        for (int kk = 0; kk < 8; ++kk) {
            short8 b0 = *(const short8*)(wp + kk * 512 + 0 * 4096);
            short8 b1 = *(const short8*)(wp + kk * 512 + 1 * 4096);
            short8 b2 = *(const short8*)(wp + kk * 512 + 2 * 4096);
            short8 b3 = *(const short8*)(wp + kk * 512 + 3 * 4096);
            short8 a0 = *(const short8*)&cur[(0 * 16 + c) * ASTRIDE + kk * 32 + q * 8];
            short8 a1 = *(const short8*)&cur[(1 * 16 + c) * ASTRIDE + kk * 32 + q * 8];
            acc[0] = __builtin_amdgcn_mfma_f32_16x16x32_bf16(a0, b0, acc[0], 0, 0, 0);
            acc[1] = __builtin_amdgcn_mfma_f32_16x16x32_bf16(a1, b0, acc[1], 0, 0, 0);
            acc[2] = __builtin_amdgcn_mfma_f32_16x16x32_bf16(a0, b1, acc[2], 0, 0, 0);
            acc[3] = __builtin_amdgcn_mfma_f32_16x16x32_bf16(a1, b1, acc[3], 0, 0, 0);
            acc[4] = __builtin_amdgcn_mfma_f32_16x16x32_bf16(a0, b2, acc[4], 0, 0, 0);
            acc[5] = __builtin_amdgcn_mfma_f32_16x16x32_bf16(a1, b2, acc[5], 0, 0, 0);
            acc[6] = __builtin_amdgcn_mfma_f32_16x16x32_bf16(a0, b3, acc[6], 0, 0, 0);
            acc[7] = __builtin_amdgcn_mfma_f32_16x16x32_bf16(a1, b3, acc[7], 0, 0, 0);
        }

        // ---- drain staged z(tile1) into Q (other buffer; no barrier needed)
        if (it == 0) {
#pragma unroll
            for (int i = 0; i < 4; ++i) {
                int idx4 = tid + i * NT;
                int r = idx4 >> 6, c4 = idx4 & 63;
                uint2v pk;
                pk.x = cvt_pk_bf16(zr[i].x, zr[i].y);
                pk.y = cvt_pk_bf16(zr[i].z, zr[i].w);
                *(uint2v*)&nxt[r * ASTRIDE + c4 * 4] = pk;
            }
        }
        __syncthreads();                 // GEMM reads of cur complete

        // ---- epilogue in 2 chunks of 16 rows; lin aliases cur -------------
#pragma unroll
        for (int h = 0; h < 2; ++h) {
            // prefetch bx/miss for this chunk's 2 tasks (hidden under lin)
            float4 xp[2];
            int    mp[2];
#pragma unroll
            for (int pp = 0; pp < 2; ++pp) {
                long bt = (row0 + h * 16 + pp * 8 + w) * Tsz + t;
                xp[pp] = *(const float4*)(bx + bt * 4);
                mp[pp] = miss[bt];
            }

            // write lin chunk (16 rows x 512 cols, bf16) into cur
#pragma unroll
            for (int ti = 0; ti < 4; ++ti) {
                int cb = w * 64 + ti * 16 + c;   // global col 0..511
                const f32x4 a = acc[ti * 2 + h];
                unsigned int p01 = cvt_pk_bf16(a[0] + bb[ti], a[1] + bb[ti]);
                unsigned int p23 = cvt_pk_bf16(a[2] + bb[ti], a[3] + bb[ti]);
                int rbase = q * 4;               // local row 0..15
                cur[(rbase + 0) * LSTRIDE + cb] = (unsigned short)(p01 & 0xffffu);
                cur[(rbase + 1) * LSTRIDE + cb] = (unsigned short)(p01 >> 16);
                cur[(rbase + 2) * LSTRIDE + cb] = (unsigned short)(p23 & 0xffffu);
                cur[(rbase + 3) * LSTRIDE + cb] = (unsigned short)(p23 >> 16);
            }
            __syncthreads();

            // postprocess: 16 rows x 64 t = 1024 tasks, 2 per thread
#pragma unroll
            for (int pp = 0; pp < 2; ++pp) {
                int rl  = pp * 8 + w;            // 0..15 (local chunk row)
                long bt = (row0 + h * 16 + rl) * Tsz + t;

                short8 l8 = *(const short8*)&cur[rl * LSTRIDE + t * 8];
                float lm[4], lv[4];
#pragma unroll
                for (int d = 0; d < 4; ++d) {
                    lm[d] = bf2f((unsigned short)l8[d]);
                    lv[d] = bf2f((unsigned short)l8[4 + d]);
                }

                float mk = (float)mp[pp];
                float xa[4] = {xp[pp].x, xp[pp].y, xp[pp].z, xp[pp].w};

                float mean_o[4], var_o[4];
                float s = sldv;
                float evp = 1.f;
#pragma unroll
                for (int d = 0; d < 4; ++d) {
                    float mean = fmaf(sqa[d], lm[d], dma[d]);
                    float v    = lv[d];
                    float sp   = fmaxf(v, 0.f) + __logf(1.f + __expf(-fabsf(v)));
                    float ev   = fminf(fmaxf(sp, EPS_), 1e20f);
                    float var  = dca[d] * ev;
                    float diff = xa[d] - mean;
                    s = fmaf(diff * diff, __builtin_amdgcn_rcpf(var), s);
                    evp *= ev;
                    mean_o[d] = mean;
                    var_o[d]  = var;
                }
                s += __logf(evp);
                float logp = -0.5f * (s + 4.f * LOG2PI_);

                float lx = logp * mk;
                out[bt]         = lx;              // log_p_x
                out[BTtot + bt] = logp - lx;       // log_p_x_missing

                *(float4*)(out + 2L * BTtot + bt * 4) =
                    (float4){mean_o[0], mean_o[1], mean_o[2], mean_o[3]};
                *(float4*)(out + 6L * BTtot + bt * 4) =
                    (float4){var_o[0], var_o[1], var_o[2], var_o[3]};
            }
            __syncthreads();             // protect cur before next lin chunk
        }
    }
}

// ---------------------------------------------------------------------------
extern "C" void kernel_launch(void* const* d_in, const int* in_sizes, int n_in,
                              void* d_out, int out_size, void* d_ws, size_t ws_size,
                              hipStream_t stream) {
    const float* z     = (const float*)d_in[0];
    const float* bx    = (const float*)d_in[1];
    const int*   miss  = (const int*)d_in[2];
    const float* dmean = (const float*)d_in[3];
    const float* dvar  = (const float*)d_in[4];
    const float* Wy    = (const float*)d_in[5];
    const float* by    = (const float*)d_in[6];
    const float* Wm    = (const float*)d_in[7];
    const float* bm    = (const float*)d_in[8];
    const float* Wv    = (const float*)d_in[9];
    const float* bv    = (const float*)d_in[10];
    float* out = (float*)d_out;

    unsigned short* weff = (unsigned short*)d_ws;                    // 256 KiB
    float* beff = (float*)((char*)d_ws + (size_t)Nsz * Zsz * 2);     // + 2 KiB

    hidec_prep<<<Tsz, Zsz, 0, stream>>>(Wy, by, Wm, bm, Wv, bv, weff, beff);
    hidec_main<<<Bsz / (2 * BM), NT, 0, stream>>>(z, bx, miss, dmean, dvar, weff, beff, out);
}

// Round 6
// 175.295 us; speedup vs baseline: 1.3122x; 1.3122x over previous
//
#include <hip/hip_runtime.h>

// ---------------------------------------------------------------------------
// HIDecoder fused: y=z@Wy^T+by ; lin_{m,v}=einsum(gamma,W{m,v})+b ; gaussian
// log-lik epilogue.  gamma never materialized:
//   Weff[n=t*8+j][k] = sum_y M_j[t][y]*Wy[t*32+y][k],  M_j = Wm(j<4)/Wv(j>=4)
//   beff[n]          = b_j[t,d] + sum_y by[t*32+y]*M_j[t][y]
// => one (32768 x 512 x 256) bf16-MFMA GEMM + elementwise epilogue.
//
// History: R3 weff pre-swizzle. R5 occupancy 33->64% (no dur change). R6
// block-wide coalesced epilogue (59us, 148MB). R7 prefetch FAILED - cap 64
// (launch_bounds ,8) had zero slack (32V+32A=64), compiler sank the loads.
// R8 2-tile pipeline FAILED - register blowup -> scratch spills (FETCH 141MiB
// WRITE 210MiB). Session law: dur = ~22us + bytes/3.65TB/s; only bytes and
// exposed latency have ever moved dur.
// R9 (this round): R6 structure + cap-128 (__launch_bounds__(512,4)) + REAL
// prefetch. 32V+32A=64 used, 64 regs slack -> prefetch dv/dm/bx x4/miss x4/
// beff after MFMA, pinned with asm "+v" before the first barrier (can't
// sink). Barrier's vmcnt(0) drain completes all waves' loads overlapped;
// postprocess runs 100% out of registers. 2 blocks/CU resident + 2 queued
// per CU (grid 1024) de-phase naturally.
// Validation bit: VGPR_Count must rise 32 -> ~56-72, else loads were sunk.
// ---------------------------------------------------------------------------

#define Bsz   32768
#define Tsz   64
#define Dsz   4
#define Ysz   32
#define Zsz   256
#define Nsz   512
#define BTtot (Bsz * Tsz)
#define EPS_  1e-3f
#define LOG2PI_ 1.8378770664093453f

#define BM       32            // batch rows per block
#define NT       512           // threads per block (8 waves)
#define ASTRIDE  264           // ushorts per staged-z row
#define LSTRIDE  524           // ushorts per lin row (512 + pad 12)

typedef __attribute__((ext_vector_type(4))) float  f32x4;
typedef __attribute__((ext_vector_type(8))) short  short8;
typedef __attribute__((ext_vector_type(2))) unsigned int uint2v;

static __device__ __forceinline__ unsigned short f2bf(float f) {
    unsigned int u = __float_as_uint(f);
    return (unsigned short)((u + 0x7fffu + ((u >> 16) & 1u)) >> 16);   // RNE
}
static __device__ __forceinline__ float bf2f(unsigned short h) {
    return __uint_as_float(((unsigned int)h) << 16);
}
// HW RNE pack: low16 = bf16(a), high16 = bf16(b)
static __device__ __forceinline__ unsigned int cvt_pk_bf16(float a, float b) {
    unsigned int r;
    asm("v_cvt_pk_bf16_f32 %0, %1, %2" : "=v"(r) : "v"(a), "v"(b));
    return r;
}

// ---------------------------------------------------------------------------
// Prep: 64 blocks (one per t) x 256 threads (one per k).
// Writes weff in B-fragment order:
//   addr(n,k) = (((tau*8+kk)*4+q)*16+c)*8 + j,  tau=n>>4, c=n&15,
//   kk=k>>5, q=(k>>3)&3, j=k&7
// ---------------------------------------------------------------------------
__global__ __launch_bounds__(256)
void hidec_prep(const float* __restrict__ Wy, const float* __restrict__ by,
                const float* __restrict__ Wm, const float* __restrict__ bm,
                const float* __restrict__ Wv, const float* __restrict__ bv,
                unsigned short* __restrict__ weff, float* __restrict__ beff) {
    __shared__ float Ml[8][Ysz];
    __shared__ float byl[Ysz];
    const int t   = blockIdx.x;          // 0..63
    const int tid = threadIdx.x;
    {
        int j = tid >> 5, y = tid & 31;
        const float* src = (j < 4) ? Wm : Wv;
        Ml[j][y] = src[(t * Dsz + (j & 3)) * Ysz + y];
    }
    if (tid < Ysz) byl[tid] = by[t * Ysz + tid];
    __syncthreads();

    const int k = tid;                   // 0..255
    const int kk = k >> 5, q = (k >> 3) & 3, je = k & 7;
    float wy[Ysz];
#pragma unroll
    for (int y = 0; y < Ysz; ++y)
        wy[y] = Wy[(size_t)(t * Ysz + y) * Zsz + k];
#pragma unroll
    for (int j = 0; j < 8; ++j) {
        float acc = 0.f;
#pragma unroll
        for (int y = 0; y < Ysz; ++y) acc = fmaf(Ml[j][y], wy[y], acc);
        int n   = t * 8 + j;
        int tau = n >> 4, c = n & 15;
        weff[((((tau * 8 + kk) * 4 + q) * 16 + c) * 8) + je] = f2bf(acc);
    }
    if (tid < 8) {
        int d = tid & 3;
        float s = ((tid < 4) ? bm : bv)[t * Dsz + d];
        for (int y = 0; y < Ysz; ++y) s = fmaf(byl[y], Ml[tid][y], s);
        beff[t * 8 + tid] = s;
    }
}

// ---------------------------------------------------------------------------
// Main: 1024 blocks x 512 threads (8 waves). Wave w owns col-tiles w*4..w*4+3
// (cols w*64..w*64+63) for 2 row-tiles of 16 (BM=32).
// ---------------------------------------------------------------------------
__global__ __launch_bounds__(NT, 4)
void hidec_main(const float* __restrict__ z, const float* __restrict__ bx,
                const int* __restrict__ miss, const float* __restrict__ dmean,
                const float* __restrict__ dvarp, const unsigned short* __restrict__ weff,
                const float* __restrict__ beff, float* __restrict__ out) {
    // a_lds (32 x 264) aliased by lin (32 x 524) after the GEMM
    __shared__ unsigned short buf[BM * LSTRIDE];         // 33536 B

    const int tid  = threadIdx.x;
    const long row0 = (long)blockIdx.x * BM;

    // ---- stage z (32 x 256 fp32) -> bf16 LDS ------------------------------
    unsigned short* a_lds = buf;
#pragma unroll
    for (int i = 0; i < 4; ++i) {
        int idx4 = tid + i * NT;         // 2048 float4-groups
        int r  = idx4 >> 6;
        int c4 = idx4 & 63;
        float4 v = *(const float4*)(z + (row0 + r) * Zsz + c4 * 4);
        uint2v pk;
        pk.x = cvt_pk_bf16(v.x, v.y);
        pk.y = cvt_pk_bf16(v.z, v.w);
        *(uint2v*)&a_lds[r * ASTRIDE + c4 * 4] = pk;
    }
    __syncthreads();

    // ---- GEMM: 32 x 512 x K=256, bf16 MFMA 16x16x32 -----------------------
    const int lane = tid & 63;
    const int w    = tid >> 6;           // wave 0..7
    const int c    = lane & 15;
    const int q    = lane >> 4;

    f32x4 acc[8];                        // [ti*2 + h]
#pragma unroll
    for (int i = 0; i < 8; ++i) acc[i] = (f32x4){0.f, 0.f, 0.f, 0.f};

    // b-fragment base: tau0 = w*4 ; per-(tau,kk) block = 512 ushorts
    const unsigned short* wp = weff + ((size_t)(w * 4) * 8) * 512 + lane * 8;

#pragma unroll
    for (int kk = 0; kk < 8; ++kk) {
        short8 b0 = *(const short8*)(wp + kk * 512 + 0 * 4096);
        short8 b1 = *(const short8*)(wp + kk * 512 + 1 * 4096);
        short8 b2 = *(const short8*)(wp + kk * 512 + 2 * 4096);
        short8 b3 = *(const short8*)(wp + kk * 512 + 3 * 4096);
        short8 a0 = *(const short8*)&a_lds[(0 * 16 + c) * ASTRIDE + kk * 32 + q * 8];
        short8 a1 = *(const short8*)&a_lds[(1 * 16 + c) * ASTRIDE + kk * 32 + q * 8];
        acc[0] = __builtin_amdgcn_mfma_f32_16x16x32_bf16(a0, b0, acc[0], 0, 0, 0);
        acc[1] = __builtin_amdgcn_mfma_f32_16x16x32_bf16(a1, b0, acc[1], 0, 0, 0);
        acc[2] = __builtin_amdgcn_mfma_f32_16x16x32_bf16(a0, b1, acc[2], 0, 0, 0);
        acc[3] = __builtin_amdgcn_mfma_f32_16x16x32_bf16(a1, b1, acc[3], 0, 0, 0);
        acc[4] = __builtin_amdgcn_mfma_f32_16x16x32_bf16(a0, b2, acc[4], 0, 0, 0);
        acc[5] = __builtin_amdgcn_mfma_f32_16x16x32_bf16(a1, b2, acc[5], 0, 0, 0);
        acc[6] = __builtin_amdgcn_mfma_f32_16x16x32_bf16(a0, b3, acc[6], 0, 0, 0);
        acc[7] = __builtin_amdgcn_mfma_f32_16x16x32_bf16(a1, b3, acc[7], 0, 0, 0);
    }

    // ---- PREFETCH all epilogue globals (issue now; cap-128 gives slack) ---
    const int t = lane;                  // fixed per thread for postprocess
    float4 dv4 = *(const float4*)(dvarp + t * 4);
    float4 dm4 = *(const float4*)(dmean + t * 4);
    float4 xp[4];
    int    mp[4];
#pragma unroll
    for (int pp = 0; pp < 4; ++pp) {
        long bt = (row0 + pp * 8 + w) * Tsz + t;
        xp[pp] = *(const float4*)(bx + bt * 4);
        mp[pp] = miss[bt];
    }
    float bb[4];
#pragma unroll
    for (int ti = 0; ti < 4; ++ti) bb[ti] = beff[w * 64 + ti * 16 + c];

    // Pin the prefetched values into registers HERE so the loads cannot be
    // sunk past the barrier (R7 failure mode). The barrier's own vmcnt(0)
    // drain completes them with all waves' loads overlapping each other.
#pragma unroll
    for (int pp = 0; pp < 4; ++pp) {
        asm volatile("" : "+v"(xp[pp].x), "+v"(xp[pp].y),
                          "+v"(xp[pp].z), "+v"(xp[pp].w), "+v"(mp[pp]));
    }
    asm volatile("" : "+v"(dv4.x), "+v"(dv4.y), "+v"(dv4.z), "+v"(dv4.w),
                      "+v"(dm4.x), "+v"(dm4.y), "+v"(dm4.z), "+v"(dm4.w));
    asm volatile("" : "+v"(bb[0]), "+v"(bb[1]), "+v"(bb[2]), "+v"(bb[3]));

    __syncthreads();                     // all waves done reading a_lds

    // ---- write lin (bf16) into LDS, block-wide ----------------------------
    unsigned short* lin = buf;           // aliases a_lds
#pragma unroll
    for (int h = 0; h < 2; ++h) {
#pragma unroll
        for (int ti = 0; ti < 4; ++ti) {
            int cb = w * 64 + ti * 16 + c;   // global col 0..511
            const f32x4 a = acc[ti * 2 + h];
            unsigned int p01 = cvt_pk_bf16(a[0] + bb[ti], a[1] + bb[ti]);
            unsigned int p23 = cvt_pk_bf16(a[2] + bb[ti], a[3] + bb[ti]);
            int rbase = h * 16 + q * 4;
            lin[(rbase + 0) * LSTRIDE + cb] = (unsigned short)(p01 & 0xffffu);
            lin[(rbase + 1) * LSTRIDE + cb] = (unsigned short)(p01 >> 16);
            lin[(rbase + 2) * LSTRIDE + cb] = (unsigned short)(p23 & 0xffffu);
            lin[(rbase + 3) * LSTRIDE + cb] = (unsigned short)(p23 >> 16);
        }
    }
    __syncthreads();

    // ---- postprocess: thread serves t = lane, rows pp*8 + w ---------------
    // everything below runs out of registers + LDS; zero global loads
    float dca[4] = {fmaxf(dv4.x, EPS_), fmaxf(dv4.y, EPS_),
                    fmaxf(dv4.z, EPS_), fmaxf(dv4.w, EPS_)};
    float sqa[4] = {sqrtf(dca[0]), sqrtf(dca[1]), sqrtf(dca[2]), sqrtf(dca[3])};
    float dma[4] = {dm4.x, dm4.y, dm4.z, dm4.w};
    float sldv = __logf(dca[0]) + __logf(dca[1]) + __logf(dca[2]) + __logf(dca[3]);

#pragma unroll
    for (int pp = 0; pp < 4; ++pp) {
        int rl  = pp * 8 + w;            // 0..31
        long bt = (row0 + rl) * Tsz + t;

        short8 l8 = *(const short8*)&lin[rl * LSTRIDE + t * 8];
        float lm[4], lv[4];
#pragma unroll
        for (int d = 0; d < 4; ++d) {
            lm[d] = bf2f((unsigned short)l8[d]);
            lv[d] = bf2f((unsigned short)l8[4 + d]);
        }

        float mk = (float)mp[pp];
        float xa[4] = {xp[pp].x, xp[pp].y, xp[pp].z, xp[pp].w};

        float mean_o[4], var_o[4];
        float s = sldv;
        float evp = 1.f;
#pragma unroll
        for (int d = 0; d < 4; ++d) {
            float mean = fmaf(sqa[d], lm[d], dma[d]);
            float v    = lv[d];
            float sp   = fmaxf(v, 0.f) + __logf(1.f + __expf(-fabsf(v)));
            float ev   = fminf(fmaxf(sp, EPS_), 1e20f);
            float var  = dca[d] * ev;
            float diff = xa[d] - mean;
            s = fmaf(diff * diff, __builtin_amdgcn_rcpf(var), s);
            evp *= ev;
            mean_o[d] = mean;
            var_o[d]  = var;
        }
        s += __logf(evp);
        float logp = -0.5f * (s + 4.f * LOG2PI_);

        float lx = logp * mk;
        out[bt]         = lx;              // log_p_x      (256B/wave contig)
        out[BTtot + bt] = logp - lx;       // log_p_x_missing

        *(float4*)(out + 2L * BTtot + bt * 4) =
            (float4){mean_o[0], mean_o[1], mean_o[2], mean_o[3]};
        *(float4*)(out + 6L * BTtot + bt * 4) =
            (float4){var_o[0], var_o[1], var_o[2], var_o[3]};
    }
}

// ---------------------------------------------------------------------------
extern "C" void kernel_launch(void* const* d_in, const int* in_sizes, int n_in,
                              void* d_out, int out_size, void* d_ws, size_t ws_size,
                              hipStream_t stream) {
    const float* z     = (const float*)d_in[0];
    const float* bx    = (const float*)d_in[1];
    const int*   miss  = (const int*)d_in[2];
    const float* dmean = (const float*)d_in[3];
    const float* dvar  = (const float*)d_in[4];
    const float* Wy    = (const float*)d_in[5];
    const float* by    = (const float*)d_in[6];
    const float* Wm    = (const float*)d_in[7];
    const float* bm    = (const float*)d_in[8];
    const float* Wv    = (const float*)d_in[9];
    const float* bv    = (const float*)d_in[10];
    float* out = (float*)d_out;

    unsigned short* weff = (unsigned short*)d_ws;                    // 256 KiB
    float* beff = (float*)((char*)d_ws + (size_t)Nsz * Zsz * 2);     // + 2 KiB

    hidec_prep<<<Tsz, Zsz, 0, stream>>>(Wy, by, Wm, bm, Wv, bv, weff, beff);
    hidec_main<<<Bsz / BM, NT, 0, stream>>>(z, bx, miss, dmean, dvar, weff, beff, out);
}